// Round 1
// baseline (1122.565 us; speedup 1.0000x reference)
//
#include <hip/hip_runtime.h>
#include <hip/hip_bf16.h>

// Problem constants
static constexpr int B_  = 16384;
static constexpr int D_  = 2048;
static constexpr int S_  = 512;
static constexpr int E_  = 8;
static constexpr int H1_ = 1024;
static constexpr int H2_ = 512;
static constexpr float EPS_ = 1e-5f;

typedef __bf16 bf16x8 __attribute__((ext_vector_type(8)));
typedef float  f32x4  __attribute__((ext_vector_type(4)));

static __device__ __forceinline__ unsigned short f2bf(float f) {
    unsigned u = __float_as_uint(f);
    unsigned r = (u + 0x7fffu + ((u >> 16) & 1u)) >> 16;   // RTNE
    return (unsigned short)r;
}

// ---------------- prepass kernels ----------------

__global__ void cvt_bf16_kernel(const float* __restrict__ in, ushort* __restrict__ out, long n) {
    long i = ((long)blockIdx.x * blockDim.x + threadIdx.x) * 4;
    long stride = (long)gridDim.x * blockDim.x * 4;
    for (; i < n; i += stride) {
        float4 v = *(const float4*)(in + i);
        ushort4 o;
        o.x = f2bf(v.x); o.y = f2bf(v.y); o.z = f2bf(v.z); o.w = f2bf(v.w);
        *(ushort4*)(out + i) = o;
    }
}

// in: [E][R][C] f32  ->  out: [E][C][R] bf16
__global__ void transpose_cvt_kernel(const float* __restrict__ in, ushort* __restrict__ out,
                                     int R, int C) {
    __shared__ float t[64][65];
    int nbr = R >> 6, nbc = C >> 6;
    int bid = blockIdx.x;
    int e = bid / (nbr * nbc);
    int rem = bid % (nbr * nbc);
    int br = (rem / nbc) << 6, bc = (rem % nbc) << 6;
    const float* ip = in + (size_t)e * R * C;
    ushort* op = out + (size_t)e * R * C;
    int tcol = (threadIdx.x & 15) * 4;
    int trow = threadIdx.x >> 4;          // 0..15
#pragma unroll
    for (int p = 0; p < 4; p++) {
        int r = trow + p * 16;
        float4 v = *(const float4*)(ip + (size_t)(br + r) * C + bc + tcol);
        t[r][tcol + 0] = v.x; t[r][tcol + 1] = v.y; t[r][tcol + 2] = v.z; t[r][tcol + 3] = v.w;
    }
    __syncthreads();
#pragma unroll
    for (int p = 0; p < 4; p++) {
        int c = trow + p * 16;            // output row (a column of input tile)
        ushort4 o;
        o.x = f2bf(t[tcol + 0][c]);
        o.y = f2bf(t[tcol + 1][c]);
        o.z = f2bf(t[tcol + 2][c]);
        o.w = f2bf(t[tcol + 3][c]);
        *(ushort4*)(op + (size_t)(bc + c) * R + br + tcol) = o;
    }
}

// fold BN into scale/shift: S = gamma*rsqrt(var+eps); T = (bias-mean)*S + beta
__global__ void fold_bn_kernel(const float* __restrict__ gamma, const float* __restrict__ beta,
                               const float* __restrict__ mean, const float* __restrict__ var,
                               const float* __restrict__ bias,
                               float* __restrict__ Sv, float* __restrict__ Tv, int n) {
    int i = blockIdx.x * 256 + threadIdx.x;
    if (i < n) {
        float s = gamma[i] * rsqrtf(var[i] + EPS_);
        Sv[i] = s;
        Tv[i] = (bias[i] - mean[i]) * s + beta[i];
    }
}

// gate: softmax(sideinfo @ Wg + bg) ; one wave per batch row
__global__ void gate_kernel(const float* __restrict__ side, const float* __restrict__ Wg,
                            const float* __restrict__ bg, float* __restrict__ gate) {
    int wid = threadIdx.x >> 6, lane = threadIdx.x & 63;
    int b = blockIdx.x * 4 + wid;
    const float* sp = side + (size_t)b * S_ + lane * 8;
    float4 v0 = *(const float4*)sp;
    float4 v1 = *(const float4*)(sp + 4);
    float sv[8] = {v0.x, v0.y, v0.z, v0.w, v1.x, v1.y, v1.z, v1.w};
    float acc[E_] = {0,0,0,0,0,0,0,0};
    const float* wrow = Wg + (size_t)(lane * 8) * E_;
#pragma unroll
    for (int j = 0; j < 8; j++) {
        float4 w0 = *(const float4*)(wrow + j * E_);
        float4 w1 = *(const float4*)(wrow + j * E_ + 4);
        acc[0] += sv[j] * w0.x; acc[1] += sv[j] * w0.y;
        acc[2] += sv[j] * w0.z; acc[3] += sv[j] * w0.w;
        acc[4] += sv[j] * w1.x; acc[5] += sv[j] * w1.y;
        acc[6] += sv[j] * w1.z; acc[7] += sv[j] * w1.w;
    }
#pragma unroll
    for (int off = 32; off; off >>= 1)
#pragma unroll
        for (int e = 0; e < E_; e++) acc[e] += __shfl_xor(acc[e], off, 64);
    float m = -1e30f;
#pragma unroll
    for (int e = 0; e < E_; e++) { acc[e] += bg[e]; m = fmaxf(m, acc[e]); }
    float s = 0.f;
#pragma unroll
    for (int e = 0; e < E_; e++) { acc[e] = __expf(acc[e] - m); s += acc[e]; }
    float inv = 1.f / s;
    if (lane < E_) gate[(size_t)b * E_ + lane] = acc[lane] * inv;
}

// ---------------- fused batched GEMM ----------------
// A: [M][K] bf16 (row-major, per-expert stride aBatch; 0 => shared)
// Bt: [E][N][K] bf16 (B transposed, K-contiguous rows)
// EPI==1: h = relu(acc*S + T) -> bf16 hout[e][row][N]
// EPI==2: out[row][N] += gate[row][e] * relu(acc*S + T)   (f32 atomics)

__device__ __forceinline__ void g2lds16(const ushort* g, ushort* l) {
    __builtin_amdgcn_global_load_lds((const __attribute__((address_space(1))) unsigned int*)g,
                                     (__attribute__((address_space(3))) unsigned int*)l,
                                     16, 0, 0);
}

template<int EPI>
__global__ __launch_bounds__(256, 2)
void gemm_fused(const ushort* __restrict__ A, const ushort* __restrict__ Bt,
                long aBatch,
                const float* __restrict__ Sv, const float* __restrict__ Tv,
                ushort* __restrict__ hout,
                float* __restrict__ outp, const float* __restrict__ gate,
                int M, int N, int K, int tilesN)
{
    __shared__ __align__(16) ushort As[128 * 64];
    __shared__ __align__(16) ushort Bs[128 * 64];

    const int tilesM = M >> 7;
    const int bid = blockIdx.x;
    const int e   = bid / (tilesM * tilesN);
    const int rem = bid % (tilesM * tilesN);
    const int tm  = rem / tilesN;
    const int tn  = rem % tilesN;

    const ushort* Ae = A + (size_t)e * aBatch + (size_t)(tm * 128) * K;
    const ushort* Be = Bt + (size_t)e * N * K + (size_t)(tn * 128) * K;

    const int tid = threadIdx.x, w = tid >> 6, lane = tid & 63;
    const int srow = lane >> 3;            // 0..7 rows within a 1KB chunk
    const int skc  = (lane & 7) * 8;       // 8 bf16 = 16B along K

    f32x4 acc[4][4] = {};

    const int wr = (w >> 1) * 64, wc = (w & 1) * 64;
    const int lr = lane & 15, lk = (lane >> 4) * 8;

    for (int kt = 0; kt < K; kt += 64) {
#pragma unroll
        for (int c = 0; c < 4; c++) {
            int q = w * 4 + c;                 // chunk 0..15 (8 rows each)
            int row = q * 8 + srow;
            g2lds16(Ae + (size_t)row * K + kt + skc, &As[q * 512]);
            g2lds16(Be + (size_t)row * K + kt + skc, &Bs[q * 512]);
        }
        __syncthreads();
#pragma unroll
        for (int ks = 0; ks < 2; ks++) {
            bf16x8 a[4], b[4];
#pragma unroll
            for (int i = 0; i < 4; i++)
                a[i] = *(const bf16x8*)&As[(wr + i * 16 + lr) * 64 + ks * 32 + lk];
#pragma unroll
            for (int i = 0; i < 4; i++)
                b[i] = *(const bf16x8*)&Bs[(wc + i * 16 + lr) * 64 + ks * 32 + lk];
#pragma unroll
            for (int i = 0; i < 4; i++)
#pragma unroll
                for (int j = 0; j < 4; j++)
                    acc[i][j] = __builtin_amdgcn_mfma_f32_16x16x32_bf16(a[i], b[j], acc[i][j], 0, 0, 0);
        }
        __syncthreads();
    }

    // epilogue: C/D layout col = lane&15, row = (lane>>4)*4 + reg
    const int rbase = tm * 128 + wr + (lane >> 4) * 4;
    const int cbase = tn * 128 + wc + lr;
#pragma unroll
    for (int j = 0; j < 4; j++) {
        const int col = cbase + j * 16;
        const float s = Sv[e * N + col];
        const float t = Tv[e * N + col];
#pragma unroll
        for (int i = 0; i < 4; i++) {
            const int row0 = rbase + i * 16;
            f32x4 v = acc[i][j];
#pragma unroll
            for (int r = 0; r < 4; r++) {
                float x = v[r] * s + t;
                x = x > 0.f ? x : 0.f;
                const int row = row0 + r;
                if (EPI == 1) {
                    hout[((size_t)e * M + row) * N + col] = f2bf(x);
                } else {
                    const float g = gate[(size_t)row * E_ + e];
                    unsafeAtomicAdd(&outp[(size_t)row * N + col], x * g);
                }
            }
        }
    }
}

// ---------------- launch ----------------

extern "C" void kernel_launch(void* const* d_in, const int* in_sizes, int n_in,
                              void* d_out, int out_size, void* d_ws, size_t ws_size,
                              hipStream_t stream) {
    (void)in_sizes; (void)n_in; (void)out_size; (void)ws_size;

    const float* input    = (const float*)d_in[0];
    const float* sideinfo = (const float*)d_in[1];
    const float* W1   = (const float*)d_in[2];
    const float* b1   = (const float*)d_in[3];
    const float* g1   = (const float*)d_in[4];
    const float* be1  = (const float*)d_in[5];
    const float* m1   = (const float*)d_in[6];
    const float* v1   = (const float*)d_in[7];
    const float* W2   = (const float*)d_in[8];
    const float* b2   = (const float*)d_in[9];
    const float* g2   = (const float*)d_in[10];
    const float* be2  = (const float*)d_in[11];
    const float* m2   = (const float*)d_in[12];
    const float* v2   = (const float*)d_in[13];
    const float* Wg   = (const float*)d_in[14];
    const float* bg   = (const float*)d_in[15];

    // workspace carve (256B aligned)
    char* w = (char*)d_ws;
    size_t off = 0;
    auto carve = [&](size_t bytes) {
        void* p = w + off;
        off += (bytes + 255) & ~(size_t)255;
        return p;
    };
    ushort* Abf  = (ushort*)carve((size_t)B_ * D_ * 2);          //  64 MB
    ushort* W1T  = (ushort*)carve((size_t)E_ * H1_ * D_ * 2);    //  32 MB
    ushort* W2T  = (ushort*)carve((size_t)E_ * H2_ * H1_ * 2);   //   8 MB
    ushort* hbuf = (ushort*)carve((size_t)E_ * B_ * H1_ * 2);    // 256 MB
    float*  S1   = (float*)carve((size_t)E_ * H1_ * 4);
    float*  T1   = (float*)carve((size_t)E_ * H1_ * 4);
    float*  S2   = (float*)carve((size_t)E_ * H2_ * 4);
    float*  T2   = (float*)carve((size_t)E_ * H2_ * 4);
    float*  gatep = (float*)carve((size_t)B_ * E_ * 4);

    float* outp = (float*)d_out;

    hipMemsetAsync(outp, 0, (size_t)B_ * H2_ * sizeof(float), stream);

    cvt_bf16_kernel<<<4096, 256, 0, stream>>>(input, Abf, (long)B_ * D_);
    transpose_cvt_kernel<<<E_ * (D_ / 64) * (H1_ / 64), 256, 0, stream>>>(W1, W1T, D_, H1_);
    transpose_cvt_kernel<<<E_ * (H1_ / 64) * (H2_ / 64), 256, 0, stream>>>(W2, W2T, H1_, H2_);
    fold_bn_kernel<<<(E_ * H1_ + 255) / 256, 256, 0, stream>>>(g1, be1, m1, v1, b1, S1, T1, E_ * H1_);
    fold_bn_kernel<<<(E_ * H2_ + 255) / 256, 256, 0, stream>>>(g2, be2, m2, v2, b2, S2, T2, E_ * H2_);
    gate_kernel<<<B_ / 4, 256, 0, stream>>>(sideinfo, Wg, bg, gatep);

    // GEMM1: [B,D] x [D,H1] per expert -> h bf16 [E][B][H1]
    gemm_fused<1><<<E_ * (B_ / 128) * (H1_ / 128), 256, 0, stream>>>(
        Abf, W1T, 0L, S1, T1, hbuf, nullptr, nullptr, B_, H1_, D_, H1_ / 128);

    // GEMM2: h[e] x [H1,H2] per expert -> out += gate * relu(bn(.))
    gemm_fused<2><<<E_ * (B_ / 128) * (H2_ / 128), 256, 0, stream>>>(
        hbuf, W2T, (long)B_ * H1_, S2, T2, nullptr, outp, gatep, B_, H2_, H1_, H2_ / 128);
}

// Round 2
// 961.244 us; speedup vs baseline: 1.1678x; 1.1678x over previous
//
#include <hip/hip_runtime.h>
#include <hip/hip_bf16.h>

// Problem constants
static constexpr int B_  = 16384;
static constexpr int D_  = 2048;
static constexpr int S_  = 512;
static constexpr int E_  = 8;
static constexpr int H1_ = 1024;
static constexpr int H2_ = 512;
static constexpr float EPS_ = 1e-5f;

typedef __bf16 bf16x8 __attribute__((ext_vector_type(8)));
typedef float  f32x4  __attribute__((ext_vector_type(4)));

static __device__ __forceinline__ unsigned short f2bf(float f) {
    unsigned u = __float_as_uint(f);
    unsigned r = (u + 0x7fffu + ((u >> 16) & 1u)) >> 16;   // RTNE
    return (unsigned short)r;
}

// ---------------- prepass kernels (unchanged from R1, verified) ----------------

__global__ void cvt_bf16_kernel(const float* __restrict__ in, ushort* __restrict__ out, long n) {
    long i = ((long)blockIdx.x * blockDim.x + threadIdx.x) * 4;
    long stride = (long)gridDim.x * blockDim.x * 4;
    for (; i < n; i += stride) {
        float4 v = *(const float4*)(in + i);
        ushort4 o;
        o.x = f2bf(v.x); o.y = f2bf(v.y); o.z = f2bf(v.z); o.w = f2bf(v.w);
        *(ushort4*)(out + i) = o;
    }
}

// in: [E][R][C] f32  ->  out: [E][C][R] bf16
__global__ void transpose_cvt_kernel(const float* __restrict__ in, ushort* __restrict__ out,
                                     int R, int C) {
    __shared__ float t[64][65];
    int nbr = R >> 6, nbc = C >> 6;
    int bid = blockIdx.x;
    int e = bid / (nbr * nbc);
    int rem = bid % (nbr * nbc);
    int br = (rem / nbc) << 6, bc = (rem % nbc) << 6;
    const float* ip = in + (size_t)e * R * C;
    ushort* op = out + (size_t)e * R * C;
    int tcol = (threadIdx.x & 15) * 4;
    int trow = threadIdx.x >> 4;
#pragma unroll
    for (int p = 0; p < 4; p++) {
        int r = trow + p * 16;
        float4 v = *(const float4*)(ip + (size_t)(br + r) * C + bc + tcol);
        t[r][tcol + 0] = v.x; t[r][tcol + 1] = v.y; t[r][tcol + 2] = v.z; t[r][tcol + 3] = v.w;
    }
    __syncthreads();
#pragma unroll
    for (int p = 0; p < 4; p++) {
        int c = trow + p * 16;
        ushort4 o;
        o.x = f2bf(t[tcol + 0][c]);
        o.y = f2bf(t[tcol + 1][c]);
        o.z = f2bf(t[tcol + 2][c]);
        o.w = f2bf(t[tcol + 3][c]);
        *(ushort4*)(op + (size_t)(bc + c) * R + br + tcol) = o;
    }
}

__global__ void fold_bn_kernel(const float* __restrict__ gamma, const float* __restrict__ beta,
                               const float* __restrict__ mean, const float* __restrict__ var,
                               const float* __restrict__ bias,
                               float* __restrict__ Sv, float* __restrict__ Tv, int n) {
    int i = blockIdx.x * 256 + threadIdx.x;
    if (i < n) {
        float s = gamma[i] * rsqrtf(var[i] + EPS_);
        Sv[i] = s;
        Tv[i] = (bias[i] - mean[i]) * s + beta[i];
    }
}

__global__ void gate_kernel(const float* __restrict__ side, const float* __restrict__ Wg,
                            const float* __restrict__ bg, float* __restrict__ gate) {
    int wid = threadIdx.x >> 6, lane = threadIdx.x & 63;
    int b = blockIdx.x * 4 + wid;
    const float* sp = side + (size_t)b * S_ + lane * 8;
    float4 v0 = *(const float4*)sp;
    float4 v1 = *(const float4*)(sp + 4);
    float sv[8] = {v0.x, v0.y, v0.z, v0.w, v1.x, v1.y, v1.z, v1.w};
    float acc[E_] = {0,0,0,0,0,0,0,0};
    const float* wrow = Wg + (size_t)(lane * 8) * E_;
#pragma unroll
    for (int j = 0; j < 8; j++) {
        float4 w0 = *(const float4*)(wrow + j * E_);
        float4 w1 = *(const float4*)(wrow + j * E_ + 4);
        acc[0] += sv[j] * w0.x; acc[1] += sv[j] * w0.y;
        acc[2] += sv[j] * w0.z; acc[3] += sv[j] * w0.w;
        acc[4] += sv[j] * w1.x; acc[5] += sv[j] * w1.y;
        acc[6] += sv[j] * w1.z; acc[7] += sv[j] * w1.w;
    }
#pragma unroll
    for (int off = 32; off; off >>= 1)
#pragma unroll
        for (int e = 0; e < E_; e++) acc[e] += __shfl_xor(acc[e], off, 64);
    float m = -1e30f;
#pragma unroll
    for (int e = 0; e < E_; e++) { acc[e] += bg[e]; m = fmaxf(m, acc[e]); }
    float s = 0.f;
#pragma unroll
    for (int e = 0; e < E_; e++) { acc[e] = __expf(acc[e] - m); s += acc[e]; }
    float inv = 1.f / s;
    if (lane < E_) gate[(size_t)b * E_ + lane] = acc[lane] * inv;
}

// ---------------- 256x256 8-phase batched GEMM (T1+T2+T3+T4+T5) ----------------
// A: [M][K] bf16 row-major (per-expert stride aBatch; 0 => shared)
// Bt: [E][N][K] bf16 (K-contiguous rows)
// LDS (dynamic, 128 KiB): A bufs @ {0,32K}, B bufs @ {64K,96K}; each 256 rows x 128 B.
// Swizzle (T2): byte-in-row ^= ((row&7)<<4). global_load_lds writes linearly, so the
// swizzle is pre-applied to the GLOBAL source column and re-applied on ds_read.

__device__ __forceinline__ void g2lds16(const void* g, void* l) {
    __builtin_amdgcn_global_load_lds((const __attribute__((address_space(1))) unsigned int*)g,
                                     (__attribute__((address_space(3))) unsigned int*)l,
                                     16, 0, 0);
}

#define BAR()     asm volatile("s_barrier" ::: "memory")
#define WAITVM6() asm volatile("s_waitcnt vmcnt(6)" ::: "memory")
#define WAITVM0() asm volatile("s_waitcnt vmcnt(0)" ::: "memory")
#define MFMA(a,b,c) __builtin_amdgcn_mfma_f32_16x16x32_bf16((a),(b),(c),0,0,0)

template<int EPI>
__global__ __launch_bounds__(512, 2)
void gemm8(const ushort* __restrict__ A, const ushort* __restrict__ Bt, long aBatch,
           const float* __restrict__ Sv, const float* __restrict__ Tv,
           ushort* __restrict__ hout, float* __restrict__ outp, const float* __restrict__ gate,
           int M, int N, int K, int tilesN, int tilesM)
{
    extern __shared__ char smem[];

    const int NT  = K >> 6;
    const int tpe = tilesM * tilesN;

    // T1: XCD-aware swizzle (grid % 8 == 0 for both GEMMs)
    const int nwg = gridDim.x, per = nwg >> 3;
    const int b0  = blockIdx.x;
    const int bid = (b0 & 7) * per + (b0 >> 3);

    const int e   = bid / tpe;
    const int rem = bid % tpe;
    const int tm  = rem / tilesN, tn = rem % tilesN;

    const char* aBase = (const char*)(A + (size_t)e * aBatch + (size_t)tm * 256 * K);
    const char* bBase = (const char*)(Bt + (size_t)e * N * K + (size_t)tn * 256 * K);
    const size_t rowB = (size_t)K * 2;

    const int tid = threadIdx.x, w = tid >> 6, lane = tid & 63;
    const int wm = w >> 2, wn = w & 3;

    // staging constants: thread covers row (tid>>3), 16B chunk (tid&7)
    const int srow = tid >> 3;
    const int scol_sw = ((tid & 7) * 16) ^ ((srow & 7) << 4);   // inverse-swizzled source col
    const int ldsStageOff = w * 1024;                            // + lane*16 by HW

    // frag-read constants (same fragment mapping as verified R1 kernel)
    const int lr = lane & 15;
    const int cks0 = ((lane >> 4) * 16) ^ ((lane & 7) << 4);
    const int cks1 = (64 + (lane >> 4) * 16) ^ ((lane & 7) << 4);
    const int rA = wm * 128 + lr;
    const int rB = wn * 64 + lr;

    auto stage = [&](int si) {
        if (si >= 4 * NT) return;
        const int tau = si >> 2, pos = si & 3, bi = tau & 1;
        const char* src; char* ldsb; int rr;
        if (pos < 2) { src = aBase; ldsb = smem + bi * 32768;        rr = pos * 128; }
        else         { src = bBase; ldsb = smem + 65536 + bi * 32768; rr = (pos - 2) * 128; }
        const char* g = src + (size_t)(rr + srow) * rowB + tau * 128 + scol_sw;
        char* l = ldsb + rr * 128 + ldsStageOff;
        g2lds16(g, l);
        g2lds16(g + 64 * rowB, l + 8192);
    };
    auto ldA = [&](int bi, int mf, int ks) {
        return *(const bf16x8*)(smem + bi * 32768 + (size_t)(rA + mf * 16) * 128 + (ks ? cks1 : cks0));
    };
    auto ldB = [&](int bi, int nf, int ks) {
        return *(const bf16x8*)(smem + 65536 + bi * 32768 + (size_t)(rB + nf * 16) * 128 + (ks ? cks1 : cks0));
    };

    f32x4 acc[8][4] = {};
    bf16x8 a0[8], a1[8], bb0[4], bb1[4];

    // prologue: tile0 fully + tile1 {A-lo,A-hi,B-lo}; B-hi(1) staged in t=0 phase 1
    for (int si = 0; si < 7; ++si) stage(si);
    WAITVM6();           // tile 0 fully landed
    BAR();

    for (int t = 0; t < NT; ++t) {
        const int bi = t & 1;
        // ---- phase 1: reads A ks0 (8) + B ks0 (4); MFMA ks0 x nh0
        #pragma unroll
        for (int mf = 0; mf < 8; ++mf) a0[mf] = ldA(bi, mf, 0);
        #pragma unroll
        for (int nf = 0; nf < 4; ++nf) bb0[nf] = ldB(bi, nf, 0);
        stage(4 * t + 7);
        BAR();
        __builtin_amdgcn_s_setprio(1);
        #pragma unroll
        for (int mf = 0; mf < 8; ++mf) {
            acc[mf][0] = MFMA(a0[mf], bb0[0], acc[mf][0]);
            acc[mf][1] = MFMA(a0[mf], bb0[1], acc[mf][1]);
        }
        __builtin_amdgcn_s_setprio(0);
        BAR();
        // ---- phase 2: reads A ks1 (8); MFMA ks0 x nh1
        #pragma unroll
        for (int mf = 0; mf < 8; ++mf) a1[mf] = ldA(bi, mf, 1);
        stage(4 * t + 8);
        BAR();
        __builtin_amdgcn_s_setprio(1);
        #pragma unroll
        for (int mf = 0; mf < 8; ++mf) {
            acc[mf][2] = MFMA(a0[mf], bb0[2], acc[mf][2]);
            acc[mf][3] = MFMA(a0[mf], bb0[3], acc[mf][3]);
        }
        __builtin_amdgcn_s_setprio(0);
        BAR();
        // ---- phase 3: reads B ks1 (4); MFMA ks1 x nh0
        #pragma unroll
        for (int nf = 0; nf < 4; ++nf) bb1[nf] = ldB(bi, nf, 1);
        stage(4 * t + 9);
        BAR();
        __builtin_amdgcn_s_setprio(1);
        #pragma unroll
        for (int mf = 0; mf < 8; ++mf) {
            acc[mf][0] = MFMA(a1[mf], bb1[0], acc[mf][0]);
            acc[mf][1] = MFMA(a1[mf], bb1[1], acc[mf][1]);
        }
        __builtin_amdgcn_s_setprio(0);
        BAR();
        // ---- phase 4: no reads; MFMA ks1 x nh1; counted vmcnt at tile boundary
        stage(4 * t + 10);
        BAR();
        __builtin_amdgcn_s_setprio(1);
        #pragma unroll
        for (int mf = 0; mf < 8; ++mf) {
            acc[mf][2] = MFMA(a1[mf], bb1[2], acc[mf][2]);
            acc[mf][3] = MFMA(a1[mf], bb1[3], acc[mf][3]);
        }
        __builtin_amdgcn_s_setprio(0);
        if (t < NT - 2)       { WAITVM6(); }   // next tile fully landed, 3 half-tiles in flight
        else if (t == NT - 2) { WAITVM0(); }   // drain before last tile
        BAR();
    }

    // epilogue: C/D layout col = lane&15, row = (lane>>4)*4 + reg
    const int rbase = tm * 256 + wm * 128 + (lane >> 4) * 4;
    const int cbase = tn * 256 + wn * 64 + lr;
#pragma unroll
    for (int nf = 0; nf < 4; ++nf) {
        const int col = cbase + nf * 16;
        const float s = Sv[e * N + col];
        const float tt = Tv[e * N + col];
#pragma unroll
        for (int mf = 0; mf < 8; ++mf) {
            const int row0 = rbase + mf * 16;
            f32x4 v = acc[mf][nf];
#pragma unroll
            for (int r = 0; r < 4; ++r) {
                float x = v[r] * s + tt;
                x = x > 0.f ? x : 0.f;
                const int row = row0 + r;
                if (EPI == 1) {
                    hout[((size_t)e * M + row) * N + col] = f2bf(x);
                } else {
                    const float g = gate[(size_t)row * E_ + e];
                    unsafeAtomicAdd(&outp[(size_t)row * N + col], x * g);
                }
            }
        }
    }
}

// ---------------- launch ----------------

extern "C" void kernel_launch(void* const* d_in, const int* in_sizes, int n_in,
                              void* d_out, int out_size, void* d_ws, size_t ws_size,
                              hipStream_t stream) {
    (void)in_sizes; (void)n_in; (void)out_size; (void)ws_size;

    const float* input    = (const float*)d_in[0];
    const float* sideinfo = (const float*)d_in[1];
    const float* W1   = (const float*)d_in[2];
    const float* b1   = (const float*)d_in[3];
    const float* g1   = (const float*)d_in[4];
    const float* be1  = (const float*)d_in[5];
    const float* m1   = (const float*)d_in[6];
    const float* v1   = (const float*)d_in[7];
    const float* W2   = (const float*)d_in[8];
    const float* b2   = (const float*)d_in[9];
    const float* g2   = (const float*)d_in[10];
    const float* be2  = (const float*)d_in[11];
    const float* m2   = (const float*)d_in[12];
    const float* v2   = (const float*)d_in[13];
    const float* Wg   = (const float*)d_in[14];
    const float* bg   = (const float*)d_in[15];

    char* w = (char*)d_ws;
    size_t off = 0;
    auto carve = [&](size_t bytes) {
        void* p = w + off;
        off += (bytes + 255) & ~(size_t)255;
        return p;
    };
    ushort* Abf  = (ushort*)carve((size_t)B_ * D_ * 2);
    ushort* W1T  = (ushort*)carve((size_t)E_ * H1_ * D_ * 2);
    ushort* W2T  = (ushort*)carve((size_t)E_ * H2_ * H1_ * 2);
    ushort* hbuf = (ushort*)carve((size_t)E_ * B_ * H1_ * 2);
    float*  S1   = (float*)carve((size_t)E_ * H1_ * 4);
    float*  T1   = (float*)carve((size_t)E_ * H1_ * 4);
    float*  S2   = (float*)carve((size_t)E_ * H2_ * 4);
    float*  T2   = (float*)carve((size_t)E_ * H2_ * 4);
    float*  gatep = (float*)carve((size_t)B_ * E_ * 4);

    float* outp = (float*)d_out;

    hipFuncSetAttribute(reinterpret_cast<const void*>(&gemm8<1>),
                        hipFuncAttributeMaxDynamicSharedMemorySize, 131072);
    hipFuncSetAttribute(reinterpret_cast<const void*>(&gemm8<2>),
                        hipFuncAttributeMaxDynamicSharedMemorySize, 131072);

    hipMemsetAsync(outp, 0, (size_t)B_ * H2_ * sizeof(float), stream);

    cvt_bf16_kernel<<<4096, 256, 0, stream>>>(input, Abf, (long)B_ * D_);
    transpose_cvt_kernel<<<E_ * (D_ / 64) * (H1_ / 64), 256, 0, stream>>>(W1, W1T, D_, H1_);
    transpose_cvt_kernel<<<E_ * (H1_ / 64) * (H2_ / 64), 256, 0, stream>>>(W2, W2T, H1_, H2_);
    fold_bn_kernel<<<(E_ * H1_ + 255) / 256, 256, 0, stream>>>(g1, be1, m1, v1, b1, S1, T1, E_ * H1_);
    fold_bn_kernel<<<(E_ * H2_ + 255) / 256, 256, 0, stream>>>(g2, be2, m2, v2, b2, S2, T2, E_ * H2_);
    gate_kernel<<<B_ / 4, 256, 0, stream>>>(sideinfo, Wg, bg, gatep);

    // GEMM1: [B,D] x [D,H1] per expert -> h bf16 [E][B][H1]
    gemm8<1><<<E_ * (B_ / 256) * (H1_ / 256), 512, 131072, stream>>>(
        Abf, W1T, 0L, S1, T1, hbuf, nullptr, nullptr, B_, H1_, D_, H1_ / 256, B_ / 256);

    // GEMM2: h[e] x [H1,H2] per expert -> out += gate * relu(bn(.))
    gemm8<2><<<E_ * (B_ / 256) * (H2_ / 256), 512, 131072, stream>>>(
        hbuf, W2T, (long)B_ * H1_, S2, T2, nullptr, outp, gatep, B_, H2_, H1_, H2_ / 256, B_ / 256);
}

// Round 4
// 913.789 us; speedup vs baseline: 1.2285x; 1.0519x over previous
//
#include <hip/hip_runtime.h>
#include <hip/hip_bf16.h>

// Problem constants
static constexpr int B_  = 16384;
static constexpr int D_  = 2048;
static constexpr int S_  = 512;
static constexpr int E_  = 8;
static constexpr int H1_ = 1024;
static constexpr int H2_ = 512;
static constexpr float EPS_ = 1e-5f;

typedef __bf16 bf16x8 __attribute__((ext_vector_type(8)));
typedef float  f32x4  __attribute__((ext_vector_type(4)));

static __device__ __forceinline__ unsigned short f2bf(float f) {
    unsigned u = __float_as_uint(f);
    unsigned r = (u + 0x7fffu + ((u >> 16) & 1u)) >> 16;   // RTNE
    return (unsigned short)r;
}

// ---------------- prepass kernels (verified R1/R2) ----------------

__global__ void cvt_bf16_kernel(const float* __restrict__ in, ushort* __restrict__ out, long n) {
    long i = ((long)blockIdx.x * blockDim.x + threadIdx.x) * 4;
    long stride = (long)gridDim.x * blockDim.x * 4;
    for (; i < n; i += stride) {
        float4 v = *(const float4*)(in + i);
        ushort4 o;
        o.x = f2bf(v.x); o.y = f2bf(v.y); o.z = f2bf(v.z); o.w = f2bf(v.w);
        *(ushort4*)(out + i) = o;
    }
}

// in: [E][R][C] f32  ->  out: [E][C][R] bf16
__global__ void transpose_cvt_kernel(const float* __restrict__ in, ushort* __restrict__ out,
                                     int R, int C) {
    __shared__ float t[64][65];
    int nbr = R >> 6, nbc = C >> 6;
    int bid = blockIdx.x;
    int e = bid / (nbr * nbc);
    int rem = bid % (nbr * nbc);
    int br = (rem / nbc) << 6, bc = (rem % nbc) << 6;
    const float* ip = in + (size_t)e * R * C;
    ushort* op = out + (size_t)e * R * C;
    int tcol = (threadIdx.x & 15) * 4;
    int trow = threadIdx.x >> 4;
#pragma unroll
    for (int p = 0; p < 4; p++) {
        int r = trow + p * 16;
        float4 v = *(const float4*)(ip + (size_t)(br + r) * C + bc + tcol);
        t[r][tcol + 0] = v.x; t[r][tcol + 1] = v.y; t[r][tcol + 2] = v.z; t[r][tcol + 3] = v.w;
    }
    __syncthreads();
#pragma unroll
    for (int p = 0; p < 4; p++) {
        int c = trow + p * 16;
        ushort4 o;
        o.x = f2bf(t[tcol + 0][c]);
        o.y = f2bf(t[tcol + 1][c]);
        o.z = f2bf(t[tcol + 2][c]);
        o.w = f2bf(t[tcol + 3][c]);
        *(ushort4*)(op + (size_t)(bc + c) * R + br + tcol) = o;
    }
}

__global__ void fold_bn_kernel(const float* __restrict__ gamma, const float* __restrict__ beta,
                               const float* __restrict__ mean, const float* __restrict__ var,
                               const float* __restrict__ bias,
                               float* __restrict__ Sv, float* __restrict__ Tv, int n) {
    int i = blockIdx.x * 256 + threadIdx.x;
    if (i < n) {
        float s = gamma[i] * rsqrtf(var[i] + EPS_);
        Sv[i] = s;
        Tv[i] = (bias[i] - mean[i]) * s + beta[i];
    }
}

__global__ void gate_kernel(const float* __restrict__ side, const float* __restrict__ Wg,
                            const float* __restrict__ bg, float* __restrict__ gate) {
    int wid = threadIdx.x >> 6, lane = threadIdx.x & 63;
    int b = blockIdx.x * 4 + wid;
    const float* sp = side + (size_t)b * S_ + lane * 8;
    float4 v0 = *(const float4*)sp;
    float4 v1 = *(const float4*)(sp + 4);
    float sv[8] = {v0.x, v0.y, v0.z, v0.w, v1.x, v1.y, v1.z, v1.w};
    float acc[E_] = {0,0,0,0,0,0,0,0};
    const float* wrow = Wg + (size_t)(lane * 8) * E_;
#pragma unroll
    for (int j = 0; j < 8; j++) {
        float4 w0 = *(const float4*)(wrow + j * E_);
        float4 w1 = *(const float4*)(wrow + j * E_ + 4);
        acc[0] += sv[j] * w0.x; acc[1] += sv[j] * w0.y;
        acc[2] += sv[j] * w0.z; acc[3] += sv[j] * w0.w;
        acc[4] += sv[j] * w1.x; acc[5] += sv[j] * w1.y;
        acc[6] += sv[j] * w1.z; acc[7] += sv[j] * w1.w;
    }
#pragma unroll
    for (int off = 32; off; off >>= 1)
#pragma unroll
        for (int e = 0; e < E_; e++) acc[e] += __shfl_xor(acc[e], off, 64);
    float m = -1e30f;
#pragma unroll
    for (int e = 0; e < E_; e++) { acc[e] += bg[e]; m = fmaxf(m, acc[e]); }
    float s = 0.f;
#pragma unroll
    for (int e = 0; e < E_; e++) { acc[e] = __expf(acc[e] - m); s += acc[e]; }
    float inv = 1.f / s;
    if (lane < E_) gate[(size_t)b * E_ + lane] = acc[lane] * inv;
}

// ---------------- 256x256 8-phase batched GEMM (T1+T2+T3+T4+T5) ----------------
// LDS map (128 KiB): B bufs at [0,65536), A bufs at [65536,131072).
// Each operand buf: bi*32768 + row*128 bytes (256 rows x 128 B), byte-swizzled
// LDS[row][x] = global[row][x ^ ((row&7)<<4)].
// NOTE: rdA*/rdB* bases bake in the REGION base; per-iteration read offset is
// ONLY bi*32768 (R3 bug: region base was added twice on the A-read path).

__device__ __forceinline__ void g2lds16(const void* g, void* l) {
    __builtin_amdgcn_global_load_lds((const __attribute__((address_space(1))) unsigned int*)g,
                                     (__attribute__((address_space(3))) unsigned int*)l,
                                     16, 0, 0);
}

#define BAR()     asm volatile("s_barrier" ::: "memory")
#define WAITVM6() asm volatile("s_waitcnt vmcnt(6)" ::: "memory")
#define WAITVM0() asm volatile("s_waitcnt vmcnt(0)" ::: "memory")
#define MFMA(a,b,c) __builtin_amdgcn_mfma_f32_16x16x32_bf16((a),(b),(c),0,0,0)

template<int EPI>
__global__ __launch_bounds__(512, 2)
void gemm8(const ushort* __restrict__ A, const ushort* __restrict__ Bt, long aBatch,
           const float* __restrict__ Sv, const float* __restrict__ Tv,
           ushort* __restrict__ hout, float* __restrict__ outp, const float* __restrict__ gate,
           int M, int N, int K, int tilesN, int tilesM)
{
    extern __shared__ char smem[];

    const int NT  = K >> 6;
    const int tpe = tilesM * tilesN;

    // T1: XCD-aware swizzle (grid % 8 == 0 for both GEMMs)
    const int nwg = gridDim.x, per = nwg >> 3;
    const int b0  = blockIdx.x;
    const int bid = (b0 & 7) * per + (b0 >> 3);

    const int e   = bid / tpe;
    const int rem = bid % tpe;
    const int tm  = rem / tilesN, tn = rem % tilesN;

    const char* aBase = (const char*)(A + (size_t)e * aBatch + (size_t)tm * 256 * K);
    const char* bBase = (const char*)(Bt + (size_t)e * N * K + (size_t)tn * 256 * K);
    const size_t rowB = (size_t)K * 2;
    const size_t half2 = 64 * rowB;     // second-load row offset (+64 rows)
    const size_t half1 = 128 * rowB;    // hi-half row offset (+128 rows)

    const int tid = threadIdx.x, w = tid >> 6, lane = tid & 63;
    const int wm = w >> 2, wn = w & 3;

    // staging: thread covers row (tid>>3), 16B chunk (tid&7); LDS dest linear = tid*16
    const int srow = tid >> 3;
    const int scol_sw = ((tid & 7) * 16) ^ ((srow & 7) << 4);   // inverse-swizzled source col
    const int ldsW = w * 1024;

    // frag-read lane constants
    const int lr = lane & 15;
    const int cks0 = ((lane >> 4) * 16) ^ ((lane & 7) << 4);
    const int cks1 = (64 + (lane >> 4) * 16) ^ ((lane & 7) << 4);
    // per-lane ds_read bases (REGION base included); {bi, frag} -> 16-bit immediates
    const char* rdA0 = smem + 65536 + (wm * 128 + lr) * 128 + cks0;
    const char* rdA1 = smem + 65536 + (wm * 128 + lr) * 128 + cks1;
    const char* rdB0 = smem + (wn * 64 + lr) * 128 + cks0;
    const char* rdB1 = smem + (wn * 64 + lr) * 128 + cks1;

    // stage dest offsets (wave-uniform base; HW appends lane*16)
    //   A half h of buf bi: 65536 + bi*32768 + h*16384 + ldsW   (+8192 for 2nd load)
    //   B half h of buf bi:          bi*32768 + h*16384 + ldsW
#define STG(gp, ldsoff) do { \
        g2lds16((gp), smem + (ldsoff)); \
        g2lds16((gp) + half2, smem + (ldsoff) + 8192); } while (0)

    // per-lane global staging pointers
    const char* ga = aBase + (size_t)srow * rowB + scol_sw;
    const char* gb = bBase + (size_t)srow * rowB + scol_sw;

    f32x4 acc[8][4] = {};
    bf16x8 a0[8], a1[8], bb0[4], bb1[4];

    // prologue: tile0 {A-lo,A-hi,B-lo,B-hi} + tile1 {A-lo,A-hi,B-lo}
    STG(ga,               65536 + 0     + 0     + ldsW);
    STG(ga + half1,       65536 + 0     + 16384 + ldsW);
    STG(gb,               0     + 0     + 0     + ldsW);
    STG(gb + half1,       0     + 0     + 16384 + ldsW);
    STG(ga + 128,         65536 + 32768 + 0     + ldsW);
    STG(ga + half1 + 128, 65536 + 32768 + 16384 + ldsW);
    STG(gb + 128,         0     + 32768 + 0     + ldsW);
    WAITVM6();            // tile 0 fully landed (8 oldest of 14)
    BAR();

    // in-loop staging pointers: pos3 stages tau=t+1; pos0..2 stage tau=t+2
    const char* sp3 = gb + half1 + 128;   // (t+1, B-hi)
    const char* sp0 = ga + 256;           // (t+2, A-lo)
    const char* sp1 = ga + half1 + 256;   // (t+2, A-hi)
    const char* sp2 = gb + 256;           // (t+2, B-lo)

#pragma unroll 2
    for (int t = 0; t < NT; ++t) {
        const int bi  = t & 1;
        const int oAr = bi * 32768;           // A READ offset (region base in rdA*)
        const int oAs = 65536 + bi * 32768;   // A STAGE base (region + buf)
        const int oB  = bi * 32768;           // B read offset / stage base (region 0)
        const int oBx = (bi ^ 1) * 32768;

        // ---- phase 1: read A ks0 (8) + B ks0 (4); stage (t+1,B-hi); MFMA ks0 x nf{0,1}
#pragma unroll
        for (int mf = 0; mf < 8; ++mf) a0[mf] = *(const bf16x8*)(rdA0 + oAr + mf * 2048);
#pragma unroll
        for (int nf = 0; nf < 4; ++nf) bb0[nf] = *(const bf16x8*)(rdB0 + oB + nf * 2048);
        if (t < NT - 1) STG(sp3, oBx + 16384 + ldsW);
        BAR();
        __builtin_amdgcn_s_setprio(1);
#pragma unroll
        for (int mf = 0; mf < 8; ++mf) {
            acc[mf][0] = MFMA(a0[mf], bb0[0], acc[mf][0]);
            acc[mf][1] = MFMA(a0[mf], bb0[1], acc[mf][1]);
        }
        __builtin_amdgcn_s_setprio(0);
        BAR();
        // ---- phase 2: read A ks1 (8); stage (t+2,A-lo); MFMA ks0 x nf{2,3}
#pragma unroll
        for (int mf = 0; mf < 8; ++mf) a1[mf] = *(const bf16x8*)(rdA1 + oAr + mf * 2048);
        if (t < NT - 2) STG(sp0, oAs + 0 + ldsW);
        BAR();
        __builtin_amdgcn_s_setprio(1);
#pragma unroll
        for (int mf = 0; mf < 8; ++mf) {
            acc[mf][2] = MFMA(a0[mf], bb0[2], acc[mf][2]);
            acc[mf][3] = MFMA(a0[mf], bb0[3], acc[mf][3]);
        }
        __builtin_amdgcn_s_setprio(0);
        BAR();
        // ---- phase 3: read B ks1 (4); stage (t+2,A-hi); MFMA ks1 x nf{0,1}
#pragma unroll
        for (int nf = 0; nf < 4; ++nf) bb1[nf] = *(const bf16x8*)(rdB1 + oB + nf * 2048);
        if (t < NT - 2) STG(sp1, oAs + 16384 + ldsW);
        BAR();
        __builtin_amdgcn_s_setprio(1);
#pragma unroll
        for (int mf = 0; mf < 8; ++mf) {
            acc[mf][0] = MFMA(a1[mf], bb1[0], acc[mf][0]);
            acc[mf][1] = MFMA(a1[mf], bb1[1], acc[mf][1]);
        }
        __builtin_amdgcn_s_setprio(0);
        BAR();
        // ---- phase 4: stage (t+2,B-lo); MFMA ks1 x nf{2,3}; counted vmcnt
        if (t < NT - 2) STG(sp2, oB + 0 + ldsW);
        BAR();
        __builtin_amdgcn_s_setprio(1);
#pragma unroll
        for (int mf = 0; mf < 8; ++mf) {
            acc[mf][2] = MFMA(a1[mf], bb1[2], acc[mf][2]);
            acc[mf][3] = MFMA(a1[mf], bb1[3], acc[mf][3]);
        }
        __builtin_amdgcn_s_setprio(0);
        if (t < NT - 2)       { WAITVM6(); }
        else if (t == NT - 2) { WAITVM0(); }
        BAR();

        sp3 += 128; sp0 += 128; sp1 += 128; sp2 += 128;
    }

    // epilogue: C/D layout col = lane&15, row = (lane>>4)*4 + reg
    const int rbase = tm * 256 + wm * 128 + (lane >> 4) * 4;
    const int cbase = tn * 256 + wn * 64 + lr;
    if (EPI == 1) {
#pragma unroll
        for (int nf = 0; nf < 4; ++nf) {
            const int col = cbase + nf * 16;
            const float s = Sv[e * N + col];
            const float tt = Tv[e * N + col];
#pragma unroll
            for (int mf = 0; mf < 8; ++mf) {
                const int row0 = rbase + mf * 16;
                f32x4 v = acc[mf][nf];
#pragma unroll
                for (int r = 0; r < 4; ++r) {
                    float x = v[r] * s + tt;
                    x = x > 0.f ? x : 0.f;
                    hout[((size_t)e * M + row0 + r) * N + col] = f2bf(x);
                }
            }
        }
    } else {
        float sc[4], tc[4];
#pragma unroll
        for (int nf = 0; nf < 4; ++nf) {
            sc[nf] = Sv[e * N + cbase + nf * 16];
            tc[nf] = Tv[e * N + cbase + nf * 16];
        }
#pragma unroll
        for (int mf = 0; mf < 8; ++mf) {
#pragma unroll
            for (int r = 0; r < 4; ++r) {
                const int row = rbase + mf * 16 + r;
                const float g = gate[(size_t)row * E_ + e];
#pragma unroll
                for (int nf = 0; nf < 4; ++nf) {
                    float x = acc[mf][nf][r] * sc[nf] + tc[nf];
                    x = x > 0.f ? x : 0.f;
                    unsafeAtomicAdd(&outp[(size_t)row * N + cbase + nf * 16], x * g);
                }
            }
        }
    }
#undef STG
}

// ---------------- launch ----------------

extern "C" void kernel_launch(void* const* d_in, const int* in_sizes, int n_in,
                              void* d_out, int out_size, void* d_ws, size_t ws_size,
                              hipStream_t stream) {
    (void)in_sizes; (void)n_in; (void)out_size; (void)ws_size;

    const float* input    = (const float*)d_in[0];
    const float* sideinfo = (const float*)d_in[1];
    const float* W1   = (const float*)d_in[2];
    const float* b1   = (const float*)d_in[3];
    const float* g1   = (const float*)d_in[4];
    const float* be1  = (const float*)d_in[5];
    const float* m1   = (const float*)d_in[6];
    const float* v1   = (const float*)d_in[7];
    const float* W2   = (const float*)d_in[8];
    const float* b2   = (const float*)d_in[9];
    const float* g2   = (const float*)d_in[10];
    const float* be2  = (const float*)d_in[11];
    const float* m2   = (const float*)d_in[12];
    const float* v2   = (const float*)d_in[13];
    const float* Wg   = (const float*)d_in[14];
    const float* bg   = (const float*)d_in[15];

    char* w = (char*)d_ws;
    size_t off = 0;
    auto carve = [&](size_t bytes) {
        void* p = w + off;
        off += (bytes + 255) & ~(size_t)255;
        return p;
    };
    ushort* Abf  = (ushort*)carve((size_t)B_ * D_ * 2);
    ushort* W1T  = (ushort*)carve((size_t)E_ * H1_ * D_ * 2);
    ushort* W2T  = (ushort*)carve((size_t)E_ * H2_ * H1_ * 2);
    ushort* hbuf = (ushort*)carve((size_t)E_ * B_ * H1_ * 2);
    float*  S1   = (float*)carve((size_t)E_ * H1_ * 4);
    float*  T1   = (float*)carve((size_t)E_ * H1_ * 4);
    float*  S2   = (float*)carve((size_t)E_ * H2_ * 4);
    float*  T2   = (float*)carve((size_t)E_ * H2_ * 4);
    float*  gatep = (float*)carve((size_t)B_ * E_ * 4);

    float* outp = (float*)d_out;

    hipFuncSetAttribute(reinterpret_cast<const void*>(&gemm8<1>),
                        hipFuncAttributeMaxDynamicSharedMemorySize, 131072);
    hipFuncSetAttribute(reinterpret_cast<const void*>(&gemm8<2>),
                        hipFuncAttributeMaxDynamicSharedMemorySize, 131072);

    hipMemsetAsync(outp, 0, (size_t)B_ * H2_ * sizeof(float), stream);

    cvt_bf16_kernel<<<4096, 256, 0, stream>>>(input, Abf, (long)B_ * D_);
    transpose_cvt_kernel<<<E_ * (D_ / 64) * (H1_ / 64), 256, 0, stream>>>(W1, W1T, D_, H1_);
    transpose_cvt_kernel<<<E_ * (H1_ / 64) * (H2_ / 64), 256, 0, stream>>>(W2, W2T, H1_, H2_);
    fold_bn_kernel<<<(E_ * H1_ + 255) / 256, 256, 0, stream>>>(g1, be1, m1, v1, b1, S1, T1, E_ * H1_);
    fold_bn_kernel<<<(E_ * H2_ + 255) / 256, 256, 0, stream>>>(g2, be2, m2, v2, b2, S2, T2, E_ * H2_);
    gate_kernel<<<B_ / 4, 256, 0, stream>>>(sideinfo, Wg, bg, gatep);

    // GEMM1: [B,D] x [D,H1] per expert -> h bf16 [E][B][H1]
    gemm8<1><<<E_ * (B_ / 256) * (H1_ / 256), 512, 131072, stream>>>(
        Abf, W1T, 0L, S1, T1, hbuf, nullptr, nullptr, B_, H1_, D_, H1_ / 256, B_ / 256);

    // GEMM2: h[e] x [H1,H2] per expert -> out += gate * relu(bn(.))
    gemm8<2><<<E_ * (B_ / 256) * (H2_ / 256), 512, 131072, stream>>>(
        hbuf, W2T, (long)B_ * H1_, S2, T2, nullptr, outp, gatep, B_, H2_, H1_, H2_ / 256, B_ / 256);
}

// Round 5
// 739.706 us; speedup vs baseline: 1.5176x; 1.2353x over previous
//
#include <hip/hip_runtime.h>
#include <hip/hip_bf16.h>

// Problem constants
static constexpr int B_  = 16384;
static constexpr int D_  = 2048;
static constexpr int S_  = 512;
static constexpr int E_  = 8;
static constexpr int H1_ = 1024;
static constexpr int H2_ = 512;
static constexpr float EPS_ = 1e-5f;

typedef __bf16 bf16x8 __attribute__((ext_vector_type(8)));
typedef float  f32x4  __attribute__((ext_vector_type(4)));

static __device__ __forceinline__ unsigned short f2bf(float f) {
    unsigned u = __float_as_uint(f);
    unsigned r = (u + 0x7fffu + ((u >> 16) & 1u)) >> 16;   // RTNE
    return (unsigned short)r;
}

// ---------------- prepass kernels (verified R1/R2) ----------------

__global__ void cvt_bf16_kernel(const float* __restrict__ in, ushort* __restrict__ out, long n) {
    long i = ((long)blockIdx.x * blockDim.x + threadIdx.x) * 4;
    long stride = (long)gridDim.x * blockDim.x * 4;
    for (; i < n; i += stride) {
        float4 v = *(const float4*)(in + i);
        ushort4 o;
        o.x = f2bf(v.x); o.y = f2bf(v.y); o.z = f2bf(v.z); o.w = f2bf(v.w);
        *(ushort4*)(out + i) = o;
    }
}

// in: [E][R][C] f32  ->  out: [E][C][R] bf16
__global__ void transpose_cvt_kernel(const float* __restrict__ in, ushort* __restrict__ out,
                                     int R, int C) {
    __shared__ float t[64][65];
    int nbr = R >> 6, nbc = C >> 6;
    int bid = blockIdx.x;
    int e = bid / (nbr * nbc);
    int rem = bid % (nbr * nbc);
    int br = (rem / nbc) << 6, bc = (rem % nbc) << 6;
    const float* ip = in + (size_t)e * R * C;
    ushort* op = out + (size_t)e * R * C;
    int tcol = (threadIdx.x & 15) * 4;
    int trow = threadIdx.x >> 4;
#pragma unroll
    for (int p = 0; p < 4; p++) {
        int r = trow + p * 16;
        float4 v = *(const float4*)(ip + (size_t)(br + r) * C + bc + tcol);
        t[r][tcol + 0] = v.x; t[r][tcol + 1] = v.y; t[r][tcol + 2] = v.z; t[r][tcol + 3] = v.w;
    }
    __syncthreads();
#pragma unroll
    for (int p = 0; p < 4; p++) {
        int c = trow + p * 16;
        ushort4 o;
        o.x = f2bf(t[tcol + 0][c]);
        o.y = f2bf(t[tcol + 1][c]);
        o.z = f2bf(t[tcol + 2][c]);
        o.w = f2bf(t[tcol + 3][c]);
        *(ushort4*)(op + (size_t)(bc + c) * R + br + tcol) = o;
    }
}

__global__ void fold_bn_kernel(const float* __restrict__ gamma, const float* __restrict__ beta,
                               const float* __restrict__ mean, const float* __restrict__ var,
                               const float* __restrict__ bias,
                               float* __restrict__ Sv, float* __restrict__ Tv, int n) {
    int i = blockIdx.x * 256 + threadIdx.x;
    if (i < n) {
        float s = gamma[i] * rsqrtf(var[i] + EPS_);
        Sv[i] = s;
        Tv[i] = (bias[i] - mean[i]) * s + beta[i];
    }
}

__global__ void gate_kernel(const float* __restrict__ side, const float* __restrict__ Wg,
                            const float* __restrict__ bg, float* __restrict__ gate) {
    int wid = threadIdx.x >> 6, lane = threadIdx.x & 63;
    int b = blockIdx.x * 4 + wid;
    const float* sp = side + (size_t)b * S_ + lane * 8;
    float4 v0 = *(const float4*)sp;
    float4 v1 = *(const float4*)(sp + 4);
    float sv[8] = {v0.x, v0.y, v0.z, v0.w, v1.x, v1.y, v1.z, v1.w};
    float acc[E_] = {0,0,0,0,0,0,0,0};
    const float* wrow = Wg + (size_t)(lane * 8) * E_;
#pragma unroll
    for (int j = 0; j < 8; j++) {
        float4 w0 = *(const float4*)(wrow + j * E_);
        float4 w1 = *(const float4*)(wrow + j * E_ + 4);
        acc[0] += sv[j] * w0.x; acc[1] += sv[j] * w0.y;
        acc[2] += sv[j] * w0.z; acc[3] += sv[j] * w0.w;
        acc[4] += sv[j] * w1.x; acc[5] += sv[j] * w1.y;
        acc[6] += sv[j] * w1.z; acc[7] += sv[j] * w1.w;
    }
#pragma unroll
    for (int off = 32; off; off >>= 1)
#pragma unroll
        for (int e = 0; e < E_; e++) acc[e] += __shfl_xor(acc[e], off, 64);
    float m = -1e30f;
#pragma unroll
    for (int e = 0; e < E_; e++) { acc[e] += bg[e]; m = fmaxf(m, acc[e]); }
    float s = 0.f;
#pragma unroll
    for (int e = 0; e < E_; e++) { acc[e] = __expf(acc[e] - m); s += acc[e]; }
    float inv = 1.f / s;
    if (lane < E_) gate[(size_t)b * E_ + lane] = acc[lane] * inv;
}

// ---------------- shared GEMM helpers ----------------

__device__ __forceinline__ void g2lds16(const void* g, void* l) {
    __builtin_amdgcn_global_load_lds((const __attribute__((address_space(1))) unsigned int*)g,
                                     (__attribute__((address_space(3))) unsigned int*)l,
                                     16, 0, 0);
}

#define BAR()      asm volatile("s_barrier" ::: "memory")
#define WAITVM(n)  asm volatile("s_waitcnt vmcnt(" #n ")" ::: "memory")
#define MFMA(a,b,c) __builtin_amdgcn_mfma_f32_16x16x32_bf16((a),(b),(c),0,0,0)

// ---------------- GEMM1: 256x256 8-phase (T1+T2+T3+T4+T5), verified R4 ----------------
// LDS map (128 KiB): B bufs at [0,65536), A bufs at [65536,131072).
// Swizzle: LDS[row][x] = global[row][x ^ ((row&7)<<4)].

template<int EPI>
__global__ __launch_bounds__(512, 2)
void gemm8(const ushort* __restrict__ A, const ushort* __restrict__ Bt, long aBatch,
           const float* __restrict__ Sv, const float* __restrict__ Tv,
           ushort* __restrict__ hout, float* __restrict__ outp, const float* __restrict__ gate,
           int M, int N, int K, int tilesN, int tilesM)
{
    extern __shared__ char smem[];

    const int NT  = K >> 6;
    const int tpe = tilesM * tilesN;

    const int nwg = gridDim.x, per = nwg >> 3;
    const int b0  = blockIdx.x;
    const int bid = (b0 & 7) * per + (b0 >> 3);

    const int e   = bid / tpe;
    const int rem = bid % tpe;
    const int tm  = rem / tilesN, tn = rem % tilesN;

    const char* aBase = (const char*)(A + (size_t)e * aBatch + (size_t)tm * 256 * K);
    const char* bBase = (const char*)(Bt + (size_t)e * N * K + (size_t)tn * 256 * K);
    const size_t rowB = (size_t)K * 2;
    const size_t half2 = 64 * rowB;
    const size_t half1 = 128 * rowB;

    const int tid = threadIdx.x, w = tid >> 6, lane = tid & 63;
    const int wm = w >> 2, wn = w & 3;

    const int srow = tid >> 3;
    const int scol_sw = ((tid & 7) * 16) ^ ((srow & 7) << 4);
    const int ldsW = w * 1024;

    const int lr = lane & 15;
    const int cks0 = ((lane >> 4) * 16) ^ ((lane & 7) << 4);
    const int cks1 = (64 + (lane >> 4) * 16) ^ ((lane & 7) << 4);
    const char* rdA0 = smem + 65536 + (wm * 128 + lr) * 128 + cks0;
    const char* rdA1 = smem + 65536 + (wm * 128 + lr) * 128 + cks1;
    const char* rdB0 = smem + (wn * 64 + lr) * 128 + cks0;
    const char* rdB1 = smem + (wn * 64 + lr) * 128 + cks1;

#define STG(gp, ldsoff) do { \
        g2lds16((gp), smem + (ldsoff)); \
        g2lds16((gp) + half2, smem + (ldsoff) + 8192); } while (0)

    const char* ga = aBase + (size_t)srow * rowB + scol_sw;
    const char* gb = bBase + (size_t)srow * rowB + scol_sw;

    f32x4 acc[8][4] = {};
    bf16x8 a0[8], a1[8], bb0[4], bb1[4];

    STG(ga,               65536 + 0     + 0     + ldsW);
    STG(ga + half1,       65536 + 0     + 16384 + ldsW);
    STG(gb,               0     + 0     + 0     + ldsW);
    STG(gb + half1,       0     + 0     + 16384 + ldsW);
    STG(ga + 128,         65536 + 32768 + 0     + ldsW);
    STG(ga + half1 + 128, 65536 + 32768 + 16384 + ldsW);
    STG(gb + 128,         0     + 32768 + 0     + ldsW);
    WAITVM(6);
    BAR();

    const char* sp3 = gb + half1 + 128;
    const char* sp0 = ga + 256;
    const char* sp1 = ga + half1 + 256;
    const char* sp2 = gb + 256;

#pragma unroll 2
    for (int t = 0; t < NT; ++t) {
        const int bi  = t & 1;
        const int oAr = bi * 32768;
        const int oAs = 65536 + bi * 32768;
        const int oB  = bi * 32768;
        const int oBx = (bi ^ 1) * 32768;

#pragma unroll
        for (int mf = 0; mf < 8; ++mf) a0[mf] = *(const bf16x8*)(rdA0 + oAr + mf * 2048);
#pragma unroll
        for (int nf = 0; nf < 4; ++nf) bb0[nf] = *(const bf16x8*)(rdB0 + oB + nf * 2048);
        if (t < NT - 1) STG(sp3, oBx + 16384 + ldsW);
        BAR();
        __builtin_amdgcn_s_setprio(1);
#pragma unroll
        for (int mf = 0; mf < 8; ++mf) {
            acc[mf][0] = MFMA(a0[mf], bb0[0], acc[mf][0]);
            acc[mf][1] = MFMA(a0[mf], bb0[1], acc[mf][1]);
        }
        __builtin_amdgcn_s_setprio(0);
        BAR();
#pragma unroll
        for (int mf = 0; mf < 8; ++mf) a1[mf] = *(const bf16x8*)(rdA1 + oAr + mf * 2048);
        if (t < NT - 2) STG(sp0, oAs + 0 + ldsW);
        BAR();
        __builtin_amdgcn_s_setprio(1);
#pragma unroll
        for (int mf = 0; mf < 8; ++mf) {
            acc[mf][2] = MFMA(a0[mf], bb0[2], acc[mf][2]);
            acc[mf][3] = MFMA(a0[mf], bb0[3], acc[mf][3]);
        }
        __builtin_amdgcn_s_setprio(0);
        BAR();
#pragma unroll
        for (int nf = 0; nf < 4; ++nf) bb1[nf] = *(const bf16x8*)(rdB1 + oB + nf * 2048);
        if (t < NT - 2) STG(sp1, oAs + 16384 + ldsW);
        BAR();
        __builtin_amdgcn_s_setprio(1);
#pragma unroll
        for (int mf = 0; mf < 8; ++mf) {
            acc[mf][0] = MFMA(a1[mf], bb1[0], acc[mf][0]);
            acc[mf][1] = MFMA(a1[mf], bb1[1], acc[mf][1]);
        }
        __builtin_amdgcn_s_setprio(0);
        BAR();
        if (t < NT - 2) STG(sp2, oB + 0 + ldsW);
        BAR();
        __builtin_amdgcn_s_setprio(1);
#pragma unroll
        for (int mf = 0; mf < 8; ++mf) {
            acc[mf][2] = MFMA(a1[mf], bb1[2], acc[mf][2]);
            acc[mf][3] = MFMA(a1[mf], bb1[3], acc[mf][3]);
        }
        __builtin_amdgcn_s_setprio(0);
        if (t < NT - 2)       { WAITVM(6); }
        else if (t == NT - 2) { WAITVM(0); }
        BAR();

        sp3 += 128; sp0 += 128; sp1 += 128; sp2 += 128;
    }

    const int rbase = tm * 256 + wm * 128 + (lane >> 4) * 4;
    const int cbase = tn * 256 + wn * 64 + lr;
    if (EPI == 1) {
#pragma unroll
        for (int nf = 0; nf < 4; ++nf) {
            const int col = cbase + nf * 16;
            const float s = Sv[e * N + col];
            const float tt = Tv[e * N + col];
#pragma unroll
            for (int mf = 0; mf < 8; ++mf) {
                const int row0 = rbase + mf * 16;
                f32x4 v = acc[mf][nf];
#pragma unroll
                for (int r = 0; r < 4; ++r) {
                    float x = v[r] * s + tt;
                    x = x > 0.f ? x : 0.f;
                    hout[((size_t)e * M + row0 + r) * N + col] = f2bf(x);
                }
            }
        }
    }
#undef STG
}

// ---------------- GEMM2e: expert-loop fused output kernel ----------------
// out[b][n] = sum_e gate[b][e] * relu(bn2_e( h[e][b][:] @ W2T[e][n][:] ))
// BM=128, BN=256; grid = (B/128) x (H2/256) = 256 blocks = 1/CU, no tail.
// Flat tau = 0..127 over (e,kt): e = tau>>4, kt = (tau&15)*64. NT deep like m201@8k.
// LDS 96 KiB: B bufs [0,65536) (2 x 32K), A bufs [65536,98304) (2 x 16K).
// 6 staging loads/thread/tile ({A-lo:1, A-hi:1, B-lo:2, B-hi:2}); steady vmcnt(4).

__global__ __launch_bounds__(512, 2)
void gemm2e(const ushort* __restrict__ H, const ushort* __restrict__ W2T,
            const float* __restrict__ Sv, const float* __restrict__ Tv,
            const float* __restrict__ gate, float* __restrict__ outp)
{
    extern __shared__ char smem[];

    // T1 swizzle: 256 blocks, 32 per XCD
    const int b0 = blockIdx.x;
    const int bid = (b0 & 7) * 32 + (b0 >> 3);
    const int tm = bid >> 1, tn = bid & 1;

    const size_t rowB  = (size_t)H1_ * 2;        // 2048 B (both operands)
    const size_t strAE = (size_t)B_ * H1_ * 2;   // expert stride of h
    const size_t strBE = (size_t)H2_ * H1_ * 2;  // expert stride of W2T
    const size_t half2 = 64 * rowB;              // +64 rows (2nd load of a B half)
    const size_t halfB = 128 * rowB;             // B-hi offset

    const int tid = threadIdx.x, w = tid >> 6, lane = tid & 63;
    const int wm = w >> 2, wn = w & 3;

    const int srow = tid >> 3;                   // 0..63
    const int scol_sw = ((tid & 7) * 16) ^ ((srow & 7) << 4);
    const int ldsW = w * 1024;

    const int lr = lane & 15;
    const int cks0 = ((lane >> 4) * 16) ^ ((lane & 7) << 4);
    const int cks1 = (64 + (lane >> 4) * 16) ^ ((lane & 7) << 4);
    const char* rdA0 = smem + 65536 + (wm * 64 + lr) * 128 + cks0;
    const char* rdA1 = smem + 65536 + (wm * 64 + lr) * 128 + cks1;
    const char* rdB0 = smem + (wn * 64 + lr) * 128 + cks0;
    const char* rdB1 = smem + (wn * 64 + lr) * 128 + cks1;

    // per-lane global staging bases (expert 0)
    const char* ga = (const char*)H + (size_t)tm * 128 * rowB + (size_t)srow * rowB + scol_sw;
    const char* gb = (const char*)W2T + (size_t)tn * 256 * rowB + (size_t)srow * rowB + scol_sw;

    // B half staged as 2 loads; A half as 1 load
#define STG2(gp, ldsoff) do { \
        g2lds16((gp), smem + (ldsoff)); \
        g2lds16((gp) + half2, smem + (ldsoff) + 8192); } while (0)

    f32x4 acc[4][4] = {};
    f32x4 oacc[4][4] = {};
    bf16x8 a0[4], a1[4], bb0[4], bb1[4];

    // prologue: tau0 {A-lo,A-hi,B-lo,B-hi} (6 loads) + tau1 {A-lo,A-hi,B-lo} (4 loads)
    g2lds16(ga,               smem + 65536 + 0     + 0    + ldsW);
    g2lds16(ga + half2,       smem + 65536 + 0     + 8192 + ldsW);
    STG2(gb,                  0     + 0     + ldsW);
    STG2(gb + halfB,          0     + 16384 + ldsW);
    g2lds16(ga + 128,         smem + 65536 + 16384 + 0    + ldsW);
    g2lds16(ga + half2 + 128, smem + 65536 + 16384 + 8192 + ldsW);
    STG2(gb + 128,            32768 + 0     + ldsW);
    WAITVM(4);
    BAR();

    const int rbase = tm * 128 + wm * 64 + (lane >> 4) * 4;
    const int cbase = tn * 256 + wn * 64 + lr;

    for (int t = 0; t < 128; ++t) {
        const int bi  = t & 1;
        const int oA  = bi * 16384;
        const int oB  = bi * 32768;

        // next-tile / next-next-tile staging sources (expert-aware)
        const int t1 = t + 1, t2 = t + 2;
        const char* gB1 = gb + (size_t)(t1 >> 4) * strBE + (t1 & 15) * 128;
        const char* gA2 = ga + (size_t)(t2 >> 4) * strAE + (t2 & 15) * 128;
        const char* gB2 = gb + (size_t)(t2 >> 4) * strBE + (t2 & 15) * 128;
        const int oA2 = 65536 + ((t2 & 1) * 16384);
        const int oB1x = (t1 & 1) * 32768;
        const int oB2 = (t2 & 1) * 32768;

        // ---- phase 1: read A ks0 + B ks0; stage (t+1,B-hi); MFMA ks0 x nf{0,1}
#pragma unroll
        for (int mf = 0; mf < 4; ++mf) a0[mf] = *(const bf16x8*)(rdA0 + oA + mf * 2048);
#pragma unroll
        for (int nf = 0; nf < 4; ++nf) bb0[nf] = *(const bf16x8*)(rdB0 + oB + nf * 2048);
        if (t1 < 128) STG2(gB1 + halfB, oB1x + 16384 + ldsW);
        BAR();
        __builtin_amdgcn_s_setprio(1);
#pragma unroll
        for (int mf = 0; mf < 4; ++mf) {
            acc[mf][0] = MFMA(a0[mf], bb0[0], acc[mf][0]);
            acc[mf][1] = MFMA(a0[mf], bb0[1], acc[mf][1]);
        }
        __builtin_amdgcn_s_setprio(0);
        BAR();
        // ---- phase 2: read A ks1; stage (t+2,A-lo); MFMA ks0 x nf{2,3}
#pragma unroll
        for (int mf = 0; mf < 4; ++mf) a1[mf] = *(const bf16x8*)(rdA1 + oA + mf * 2048);
        if (t2 < 128) {
            g2lds16(gA2, smem + oA2 + 0 + ldsW);
        }
        BAR();
        __builtin_amdgcn_s_setprio(1);
#pragma unroll
        for (int mf = 0; mf < 4; ++mf) {
            acc[mf][2] = MFMA(a0[mf], bb0[2], acc[mf][2]);
            acc[mf][3] = MFMA(a0[mf], bb0[3], acc[mf][3]);
        }
        __builtin_amdgcn_s_setprio(0);
        BAR();
        // ---- phase 3: read B ks1; stage (t+2,A-hi); MFMA ks1 x nf{0,1}
#pragma unroll
        for (int nf = 0; nf < 4; ++nf) bb1[nf] = *(const bf16x8*)(rdB1 + oB + nf * 2048);
        if (t2 < 128) {
            g2lds16(gA2 + half2, smem + oA2 + 8192 + ldsW);
        }
        BAR();
        __builtin_amdgcn_s_setprio(1);
#pragma unroll
        for (int mf = 0; mf < 4; ++mf) {
            acc[mf][0] = MFMA(a1[mf], bb1[0], acc[mf][0]);
            acc[mf][1] = MFMA(a1[mf], bb1[1], acc[mf][1]);
        }
        __builtin_amdgcn_s_setprio(0);
        BAR();
        // ---- phase 4: stage (t+2,B-lo); MFMA ks1 x nf{2,3}; counted vmcnt
        if (t2 < 128) STG2(gB2, oB2 + 0 + ldsW);
        BAR();
        __builtin_amdgcn_s_setprio(1);
#pragma unroll
        for (int mf = 0; mf < 4; ++mf) {
            acc[mf][2] = MFMA(a1[mf], bb1[2], acc[mf][2]);
            acc[mf][3] = MFMA(a1[mf], bb1[3], acc[mf][3]);
        }
        __builtin_amdgcn_s_setprio(0);
        if (t < 126)       { WAITVM(4); }
        else if (t == 126) { WAITVM(0); }
        BAR();

        // ---- expert boundary: fold acc into gate-weighted out accumulator
        if ((t & 15) == 15) {
            const int e = t >> 4;
            float sc[4], tc[4];
#pragma unroll
            for (int nf = 0; nf < 4; ++nf) {
                sc[nf] = Sv[e * H2_ + cbase + nf * 16];
                tc[nf] = Tv[e * H2_ + cbase + nf * 16];
            }
#pragma unroll
            for (int mf = 0; mf < 4; ++mf) {
#pragma unroll
                for (int r = 0; r < 4; ++r) {
                    const int row = rbase + mf * 16 + r;
                    const float g = gate[(size_t)row * E_ + e];
#pragma unroll
                    for (int nf = 0; nf < 4; ++nf) {
                        float x = acc[mf][nf][r] * sc[nf] + tc[nf];
                        x = x > 0.f ? x : 0.f;
                        oacc[mf][nf][r] += g * x;
                    }
                }
            }
#pragma unroll
            for (int mf = 0; mf < 4; ++mf)
#pragma unroll
                for (int nf = 0; nf < 4; ++nf)
                    acc[mf][nf] = (f32x4){0.f, 0.f, 0.f, 0.f};
        }
    }

    // final write (each element owned by exactly one block)
#pragma unroll
    for (int mf = 0; mf < 4; ++mf) {
#pragma unroll
        for (int r = 0; r < 4; ++r) {
            const int row = rbase + mf * 16 + r;
#pragma unroll
            for (int nf = 0; nf < 4; ++nf)
                outp[(size_t)row * H2_ + cbase + nf * 16] = oacc[mf][nf][r];
        }
    }
#undef STG2
}

// ---------------- launch ----------------

extern "C" void kernel_launch(void* const* d_in, const int* in_sizes, int n_in,
                              void* d_out, int out_size, void* d_ws, size_t ws_size,
                              hipStream_t stream) {
    (void)in_sizes; (void)n_in; (void)out_size; (void)ws_size;

    const float* input    = (const float*)d_in[0];
    const float* sideinfo = (const float*)d_in[1];
    const float* W1   = (const float*)d_in[2];
    const float* b1   = (const float*)d_in[3];
    const float* g1   = (const float*)d_in[4];
    const float* be1  = (const float*)d_in[5];
    const float* m1   = (const float*)d_in[6];
    const float* v1   = (const float*)d_in[7];
    const float* W2   = (const float*)d_in[8];
    const float* b2   = (const float*)d_in[9];
    const float* g2   = (const float*)d_in[10];
    const float* be2  = (const float*)d_in[11];
    const float* m2   = (const float*)d_in[12];
    const float* v2   = (const float*)d_in[13];
    const float* Wg   = (const float*)d_in[14];
    const float* bg   = (const float*)d_in[15];

    char* w = (char*)d_ws;
    size_t off = 0;
    auto carve = [&](size_t bytes) {
        void* p = w + off;
        off += (bytes + 255) & ~(size_t)255;
        return p;
    };
    ushort* Abf  = (ushort*)carve((size_t)B_ * D_ * 2);
    ushort* W1T  = (ushort*)carve((size_t)E_ * H1_ * D_ * 2);
    ushort* W2T  = (ushort*)carve((size_t)E_ * H2_ * H1_ * 2);
    ushort* hbuf = (ushort*)carve((size_t)E_ * B_ * H1_ * 2);
    float*  S1   = (float*)carve((size_t)E_ * H1_ * 4);
    float*  T1   = (float*)carve((size_t)E_ * H1_ * 4);
    float*  S2   = (float*)carve((size_t)E_ * H2_ * 4);
    float*  T2   = (float*)carve((size_t)E_ * H2_ * 4);
    float*  gatep = (float*)carve((size_t)B_ * E_ * 4);

    float* outp = (float*)d_out;

    hipFuncSetAttribute(reinterpret_cast<const void*>(&gemm8<1>),
                        hipFuncAttributeMaxDynamicSharedMemorySize, 131072);
    hipFuncSetAttribute(reinterpret_cast<const void*>(&gemm2e),
                        hipFuncAttributeMaxDynamicSharedMemorySize, 98304);

    cvt_bf16_kernel<<<4096, 256, 0, stream>>>(input, Abf, (long)B_ * D_);
    transpose_cvt_kernel<<<E_ * (D_ / 64) * (H1_ / 64), 256, 0, stream>>>(W1, W1T, D_, H1_);
    transpose_cvt_kernel<<<E_ * (H1_ / 64) * (H2_ / 64), 256, 0, stream>>>(W2, W2T, H1_, H2_);
    fold_bn_kernel<<<(E_ * H1_ + 255) / 256, 256, 0, stream>>>(g1, be1, m1, v1, b1, S1, T1, E_ * H1_);
    fold_bn_kernel<<<(E_ * H2_ + 255) / 256, 256, 0, stream>>>(g2, be2, m2, v2, b2, S2, T2, E_ * H2_);
    gate_kernel<<<B_ / 4, 256, 0, stream>>>(sideinfo, Wg, bg, gatep);

    // GEMM1: [B,D] x [D,H1] per expert -> h bf16 [E][B][H1]
    gemm8<1><<<E_ * (B_ / 256) * (H1_ / 256), 512, 131072, stream>>>(
        Abf, W1T, 0L, S1, T1, hbuf, nullptr, nullptr, B_, H1_, D_, H1_ / 256, B_ / 256);

    // GEMM2e: expert-loop, gate-weighted, writes out exactly once (no atomics)
    gemm2e<<<(B_ / 128) * (H2_ / 256), 512, 98304, stream>>>(
        hbuf, W2T, S2, T2, gatep, outp);
}